// Round 2
// baseline (601.314 us; speedup 1.0000x reference)
//
#include <hip/hip_runtime.h>

// MeanAggregator: out[b][:] = mean_{s<10} features[neigh_idx[b][s]][:]
// B=50000, S=10, N=1e6, D=128, fp32. Latency/queue-bound random gather.
//
// Round-5 = round-4's structural change with the risky gather asm removed.
//  - Indices via SMEM: the 4 idx rows a wave needs (P0,P0+1 and their +halfB
//    partners) are wave-uniform and 16B-aligned (P0 is even, halfB even), so
//    10x s_load_dwordx4 in one asm block (lgkm path). Removes 20 VMEM idx
//    loads/wave from the TCP queue and the vmcnt path; gathers are now the
//    only vmcnt items.
//  - Gathers in plain C as base + zext(u32 offset): LLVM folds this into
//    saddr-form global_load_dwordx4 (scalar base, 32-bit voffset), cutting
//    per-gather address math to ~2 VALU. Compiler schedules all 20 loads
//    before the sums and inserts staged vmcnt drains (proven behavior of the
//    600us kernel).
//  - No manual vmcnt / sc0 this round: isolate the idx-path change, keep
//    pass-probability high after the container fault.
// __launch_bounds__(256,4): ~100 VGPRs, 4 waves/SIMD resident.

typedef float v4f __attribute__((ext_vector_type(4)));
typedef int   i4v __attribute__((ext_vector_type(4)));

constexpr int D      = 128;
constexpr int CHUNKS = D / 4;   // 32 lanes per row (float4 chunks)
constexpr int S      = 10;      // num_sample (fixed in reference)

__global__ __launch_bounds__(256, 4)
void mean_agg_kernel(const int* __restrict__ idx,
                     const float* __restrict__ feat,
                     float* __restrict__ out,
                     int halfB)
{
    const int tid  = blockIdx.x * blockDim.x + threadIdx.x;
    const int c    = tid & 31;         // float4 chunk within row
    const int pair = tid >> 5;         // which row-pair
    if (pair >= halfB) return;         // grid is exact for B=50000; safety only

    // Wave-uniform base pair: lanes 0-31 handle pair P0, lanes 32-63 pair P0+1.
    // P0 is even (waves are 64-thread aligned), so P0*40B and (P0+halfB)*40B
    // are both 16B-aligned -> s_load_dwordx4 naturally aligned.
    const int  P0 = __builtin_amdgcn_readfirstlane(pair);
    const bool hi = (threadIdx.x & 32) != 0;

    const int* qa = idx + (size_t)P0 * S;                      // rows P0, P0+1
    const int* qb = idx + ((size_t)P0 + (size_t)halfB) * S;    // partner rows

    i4v ia0, ia1, ia2, ia3, ia4, ib0, ib1, ib2, ib3, ib4;
    asm volatile(
        "s_load_dwordx4 %0, %10, 0x0\n\t"
        "s_load_dwordx4 %1, %10, 0x10\n\t"
        "s_load_dwordx4 %2, %10, 0x20\n\t"
        "s_load_dwordx4 %3, %10, 0x30\n\t"
        "s_load_dwordx4 %4, %10, 0x40\n\t"
        "s_load_dwordx4 %5, %11, 0x0\n\t"
        "s_load_dwordx4 %6, %11, 0x10\n\t"
        "s_load_dwordx4 %7, %11, 0x20\n\t"
        "s_load_dwordx4 %8, %11, 0x30\n\t"
        "s_load_dwordx4 %9, %11, 0x40\n\t"
        "s_waitcnt lgkmcnt(0)"
        : "=&s"(ia0), "=&s"(ia1), "=&s"(ia2), "=&s"(ia3), "=&s"(ia4),
          "=&s"(ib0), "=&s"(ib1), "=&s"(ib2), "=&s"(ib3), "=&s"(ib4)
        : "s"(qa), "s"(qb));
    // Consumers depend on this block's register defs (same asm as the
    // waitcnt), so no sched_barrier needed: dataflow already orders them.

    // Unpack to scalar arrays (constant indices after unroll -> SGPRs).
    int A[2 * S], Bq[2 * S];
#pragma unroll
    for (int k = 0; k < 4; ++k) {
        A[k]       = ia0[k]; A[4 + k]   = ia1[k]; A[8 + k]   = ia2[k];
        A[12 + k]  = ia3[k]; A[16 + k]  = ia4[k];
        Bq[k]      = ib0[k]; Bq[4 + k]  = ib1[k]; Bq[8 + k]  = ib2[k];
        Bq[12 + k] = ib3[k]; Bq[16 + k] = ib4[k];
    }

    const unsigned cbyte = (unsigned)c << 4;    // c*16 bytes within the row
    const char* fbase = (const char*)feat;

    // 20 gathers, saddr form: address = uniform base + zext(u32 offset).
    // Offsets < 512MB so zext == sext; LLVM folds into global_load_*_SADDR.
    v4f v[2 * S];
#pragma unroll
    for (int s = 0; s < S; ++s) {
        const int      r   = hi ? A[S + s] : A[s];        // cndmask select
        const unsigned off = ((unsigned)r << 9) + cbyte;  // idx*512 + c*16
        v[s] = *(const v4f*)(fbase + (size_t)off);
    }
#pragma unroll
    for (int s = 0; s < S; ++s) {
        const int      r   = hi ? Bq[S + s] : Bq[s];
        const unsigned off = ((unsigned)r << 9) + cbyte;
        v[S + s] = *(const v4f*)(fbase + (size_t)off);
    }

    v4f a0 = (v4f)(0.f);
    v4f a1 = (v4f)(0.f);
#pragma unroll
    for (int s = 0; s < S; ++s) {
        a0 += v[s];
        a1 += v[S + s];
    }

    constexpr float invS = 1.0f / S;
    a0 *= invS;
    a1 *= invS;

    __builtin_nontemporal_store(a0, (v4f*)(out + (size_t)pair * D + c * 4));
    __builtin_nontemporal_store(a1, (v4f*)(out + ((size_t)pair + (size_t)halfB) * D + c * 4));
}

extern "C" void kernel_launch(void* const* d_in, const int* in_sizes, int n_in,
                              void* d_out, int out_size, void* d_ws, size_t ws_size,
                              hipStream_t stream) {
    const int*   idx  = (const int*)d_in[0];    // [B, S] int
    const float* feat = (const float*)d_in[1];  // [N, D] fp32
    float*       out  = (float*)d_out;          // [B, D] fp32

    const int B     = out_size / D;             // 50000
    const int halfB = B / 2;                    // 25000 (B is even)

    const int threads = 256;
    const int total   = halfB * CHUNKS;         // one thread per 2 rows x chunk
    const int blocks  = (total + threads - 1) / threads;

    mean_agg_kernel<<<blocks, threads, 0, stream>>>(idx, feat, out, halfB);
}